// Round 1
// baseline (186.303 us; speedup 1.0000x reference)
//
#include <hip/hip_runtime.h>
#include <math.h>

// Problem constants
#define B_    256
#define S_    196
#define DIM_  768
#define D4_   192          // DIM/4
#define POOL_ 1024
#define LEN_  8
#define TOPK_ 8

// Output layout (fp32, concatenated flat in return order)
//  prompted_embedding: [256, 260, 768]  = 51,118,080
//  reduce_sim        : scalar           = 1
//  similarity        : [256, 1024]      = 262,144
//  idx               : [256, 8]         = 2,048
#define PE_ELEMS   51118080L
#define RS_OFF     51118080L
#define SIM_OFF    51118081L
#define IDX_OFF    51380225L

// Workspace layout (floats unless noted)
#define WS_XMEAN   0L                      // 256*768
#define WS_XNORM   196608L                 // 256*768
#define WS_PNORM   393216L                 // 1024*768
#define WS_PNORMT  1179648L                // 768*1024 (transposed)
#define WS_COUNTS  1966080L                // 1024 int
#define WS_MAJOR   1967104L                // 8 int

// ---------------------------------------------------------------------------
// K1: mean over S + copy x_embed into prompted_embedding[:, 64:260, :]
// grid = 256*3 blocks (b, col-chunk), block = 256 (4 s-phases x 64 float4 cols)
// ---------------------------------------------------------------------------
__global__ void mean_copy_kernel(const float4* __restrict__ x4,
                                 float4* __restrict__ out4,
                                 float4* __restrict__ xmean4) {
    int b  = blockIdx.x / 3;
    int c  = blockIdx.x % 3;
    int t  = threadIdx.x;
    int col = (t & 63) + c * 64;   // float4 column 0..191
    int sl  = t >> 6;              // 0..3
    const float4* xr = x4  + (long)b * S_ * D4_ + col;
    float4*       ow = out4 + ((long)b * 260 + 64) * D4_ + col;
    float4 acc = {0.f, 0.f, 0.f, 0.f};
    #pragma unroll 4
    for (int s = sl; s < S_; s += 4) {
        float4 v = xr[(long)s * D4_];
        acc.x += v.x; acc.y += v.y; acc.z += v.z; acc.w += v.w;
        ow[(long)s * D4_] = v;
    }
    __shared__ float4 part[256];
    part[t] = acc;
    __syncthreads();
    if (t < 64) {
        float4 a = part[t], b1 = part[t + 64], c1 = part[t + 128], d1 = part[t + 192];
        float4 m;
        m.x = (a.x + b1.x + c1.x + d1.x) / 196.f;
        m.y = (a.y + b1.y + c1.y + d1.y) / 196.f;
        m.z = (a.z + b1.z + c1.z + d1.z) / 196.f;
        m.w = (a.w + b1.w + c1.w + d1.w) / 196.f;
        xmean4[(long)b * D4_ + col] = m;
    }
}

// ---------------------------------------------------------------------------
// K2: row-wise L2 normalize. block=192 threads (1 float4/thread), grid=rows.
// Optionally also writes a transposed copy (for the similarity kernel).
// ---------------------------------------------------------------------------
__global__ void l2norm_kernel(const float4* __restrict__ in4,
                              float4* __restrict__ out4,
                              float* __restrict__ outT, int strideT) {
    int r = blockIdx.x, t = threadIdx.x;   // t in [0,192)
    float4 v = in4[(long)r * D4_ + t];
    float ss = v.x * v.x + v.y * v.y + v.z * v.z + v.w * v.w;
    #pragma unroll
    for (int off = 32; off > 0; off >>= 1) ss += __shfl_xor(ss, off);
    __shared__ float wss[3];
    if ((t & 63) == 0) wss[t >> 6] = ss;
    __syncthreads();
    float tot = wss[0] + wss[1] + wss[2];
    float scale = 1.0f / sqrtf(fmaxf(tot, 1e-12f));
    float4 o = {v.x * scale, v.y * scale, v.z * scale, v.w * scale};
    out4[(long)r * D4_ + t] = o;
    if (outT) {
        int d = t * 4;
        outT[(long)d       * strideT + r] = o.x;
        outT[(long)(d + 1) * strideT + r] = o.y;
        outT[(long)(d + 2) * strideT + r] = o.z;
        outT[(long)(d + 3) * strideT + r] = o.w;
    }
}

// ---------------------------------------------------------------------------
// K3: similarity = xnorm [256,768] @ pnormT [768,1024] -> [256,1024] fp32
// grid = (64 b-groups, 4 p-chunks), block = 256. LDS stages 4 x-rows.
// ---------------------------------------------------------------------------
__global__ void sim_kernel(const float* __restrict__ xnorm,
                           const float* __restrict__ pT,
                           float* __restrict__ sim) {
    __shared__ float xs[4 * DIM_];
    int bg = blockIdx.x;    // 0..63
    int pc = blockIdx.y;    // 0..3
    int t  = threadIdx.x;
    const float* xr = xnorm + (long)bg * 4 * DIM_;
    for (int i = t; i < 4 * DIM_; i += 256) xs[i] = xr[i];
    __syncthreads();
    int p = pc * 256 + t;
    float a0 = 0.f, a1 = 0.f, a2 = 0.f, a3 = 0.f;
    const float* pcol = pT + p;
    #pragma unroll 4
    for (int d = 0; d < DIM_; ++d) {
        float w = pcol[(long)d * POOL_];
        a0 += xs[d] * w;
        a1 += xs[DIM_ + d] * w;
        a2 += xs[2 * DIM_ + d] * w;
        a3 += xs[3 * DIM_ + d] * w;
    }
    long ob = (long)bg * 4 * POOL_ + p;
    sim[ob]            = a0;
    sim[ob + POOL_]    = a1;
    sim[ob + 2 * POOL_] = a2;
    sim[ob + 3 * POOL_] = a3;
}

// ---------------------------------------------------------------------------
// K4: per-row top-8 (ties -> smallest index), atomicAdd into counts.
// One wave per row.
// ---------------------------------------------------------------------------
__global__ void row_topk_kernel(const float* __restrict__ sim,
                                int* __restrict__ counts) {
    int row  = blockIdx.x;
    int lane = threadIdx.x;      // 64
    float v[16];
    const float* r = sim + (long)row * POOL_;
    #pragma unroll
    for (int j = 0; j < 16; ++j) v[j] = r[lane + j * 64];
    for (int it = 0; it < TOPK_; ++it) {
        float bv = v[0];
        int   bi = lane;
        #pragma unroll
        for (int j = 1; j < 16; ++j) {
            if (v[j] > bv) { bv = v[j]; bi = lane + j * 64; }  // keep-first => smallest idx
        }
        #pragma unroll
        for (int off = 32; off > 0; off >>= 1) {
            float ov = __shfl_xor(bv, off);
            int   oi = __shfl_xor(bi, off);
            if (ov > bv || (ov == bv && oi < bi)) { bv = ov; bi = oi; }
        }
        if ((bi & 63) == lane) v[bi >> 6] = -INFINITY;
        if (lane == 0) atomicAdd(&counts[bi], 1);
    }
}

// ---------------------------------------------------------------------------
// K5: top-8 of counts (ties -> smallest pool id) + broadcast idx output.
// Single wave.
// ---------------------------------------------------------------------------
__global__ void count_topk_kernel(const int* __restrict__ counts,
                                  int* __restrict__ major,
                                  float* __restrict__ idx_out) {
    int lane = threadIdx.x;  // 64
    int v[16];
    #pragma unroll
    for (int j = 0; j < 16; ++j) v[j] = counts[lane + j * 64];
    __shared__ int maj[TOPK_];
    for (int it = 0; it < TOPK_; ++it) {
        int bv = v[0];
        int bi = lane;
        #pragma unroll
        for (int j = 1; j < 16; ++j) {
            if (v[j] > bv) { bv = v[j]; bi = lane + j * 64; }
        }
        #pragma unroll
        for (int off = 32; off > 0; off >>= 1) {
            int ov = __shfl_xor(bv, off);
            int oi = __shfl_xor(bi, off);
            if (ov > bv || (ov == bv && oi < bi)) { bv = ov; bi = oi; }
        }
        if (lane == 0) { major[it] = bi; maj[it] = bi; }
        if ((bi & 63) == lane) v[bi >> 6] = -1;
    }
    __syncthreads();
    for (int i = lane; i < B_ * TOPK_; i += 64) idx_out[i] = (float)maj[i & 7];
}

// ---------------------------------------------------------------------------
// K6: reduce_sim = sum_k sum_b sim[b, major_k] / B
// ---------------------------------------------------------------------------
__global__ void reduce_sim_kernel(const float* __restrict__ sim,
                                  const int* __restrict__ major,
                                  float* __restrict__ out_scalar) {
    __shared__ float red[256];
    int t = threadIdx.x;    // == b
    float s = 0.f;
    const float* r = sim + (long)t * POOL_;
    #pragma unroll
    for (int k = 0; k < TOPK_; ++k) s += r[major[k]];
    red[t] = s;
    __syncthreads();
    for (int off = 128; off > 0; off >>= 1) {
        if (t < off) red[t] += red[t + off];
        __syncthreads();
    }
    if (t == 0) *out_scalar = red[0] / (float)B_;
}

// ---------------------------------------------------------------------------
// K7: gather the 8 major prompts -> prompted_embedding[:, 0:64, :]
// ---------------------------------------------------------------------------
__global__ void gather_kernel(const float4* __restrict__ prompt4,
                              const int* __restrict__ major,
                              float4* __restrict__ out4) {
    long g = (long)blockIdx.x * 256 + threadIdx.x;  // < 256*64*192
    int d4 = (int)(g % D4_);
    int kl = (int)((g / D4_) % 64);
    int b  = (int)(g / (D4_ * 64));
    int k = kl >> 3, l = kl & 7;
    int pid = major[k];
    out4[((long)b * 260 + kl) * D4_ + d4] = prompt4[((long)pid * LEN_ + l) * D4_ + d4];
}

// ---------------------------------------------------------------------------
extern "C" void kernel_launch(void* const* d_in, const int* in_sizes, int n_in,
                              void* d_out, int out_size, void* d_ws, size_t ws_size,
                              hipStream_t stream) {
    const float* x_embed    = (const float*)d_in[0];
    const float* prompt     = (const float*)d_in[1];
    const float* prompt_key = (const float*)d_in[2];
    float* out = (float*)d_out;
    float* ws  = (float*)d_ws;

    float* xmean  = ws + WS_XMEAN;
    float* xnorm  = ws + WS_XNORM;
    float* pnorm  = ws + WS_PNORM;
    float* pnormT = ws + WS_PNORMT;
    int*   counts = (int*)(ws + WS_COUNTS);
    int*   major  = (int*)(ws + WS_MAJOR);

    float* out_pe  = out;                 // prompted_embedding
    float* out_rs  = out + RS_OFF;        // reduce_sim scalar
    float* out_sim = out + SIM_OFF;       // similarity [256,1024]
    float* out_idx = out + IDX_OFF;       // idx [256,8] (as float)

    // zero the count bins (ws is poisoned, not re-zeroed between replays)
    hipMemsetAsync(counts, 0, POOL_ * sizeof(int), stream);

    // prompt_key -> pnorm (+ transposed copy)
    l2norm_kernel<<<POOL_, 192, 0, stream>>>((const float4*)prompt_key,
                                             (float4*)pnorm, pnormT, POOL_);
    // mean over S + concat copy
    mean_copy_kernel<<<B_ * 3, 256, 0, stream>>>((const float4*)x_embed,
                                                 (float4*)out_pe, (float4*)xmean);
    // xmean -> xnorm
    l2norm_kernel<<<B_, 192, 0, stream>>>((const float4*)xmean,
                                          (float4*)xnorm, nullptr, 0);
    // similarity
    dim3 sgrid(64, 4);
    sim_kernel<<<sgrid, 256, 0, stream>>>(xnorm, pnormT, out_sim);
    // per-row top-8 -> counts
    row_topk_kernel<<<B_, 64, 0, stream>>>(out_sim, counts);
    // consensus top-8 + idx output
    count_topk_kernel<<<1, 64, 0, stream>>>(counts, major, out_idx);
    // reduce_sim
    reduce_sim_kernel<<<1, 256, 0, stream>>>(out_sim, major, out_rs);
    // gather prompts into output head
    gather_kernel<<<(B_ * 64 * D4_) / 256, 256, 0, stream>>>((const float4*)prompt,
                                                             major, (float4*)out_pe);
}

// Round 2
// 178.450 us; speedup vs baseline: 1.0440x; 1.0440x over previous
//
#include <hip/hip_runtime.h>
#include <math.h>

// Problem constants
#define B_    256
#define S_    196
#define DIM_  768
#define D4_   192          // DIM/4
#define POOL_ 1024
#define LEN_  8
#define TOPK_ 8

// Output layout (fp32, concatenated flat in return order)
//  prompted_embedding: [256, 260, 768]  = 51,118,080
//  reduce_sim        : scalar           = 1
//  similarity        : [256, 1024]      = 262,144
//  idx               : [256, 8]         = 2,048
#define RS_OFF     51118080L
#define SIM_OFF    51118081L
#define IDX_OFF    51380225L

// Workspace layout (float offsets)
#define WS_XMEAN   0L          // 256*768            = 196608
#define WS_PNORMT  196608L     // 768*1024 transposed = 786432
#define WS_ROWIDS  983040L     // 256*8 int
#define WS_MAJOR   985088L     // 8 int

// ---------------------------------------------------------------------------
// K1: mean over S + copy x_embed into prompted_embedding[:, 64:260, :]
// grid = 256*3 blocks (b, col-chunk), block = 256 (4 s-phases x 64 float4 cols)
// ---------------------------------------------------------------------------
__global__ void mean_copy_kernel(const float4* __restrict__ x4,
                                 float4* __restrict__ out4,
                                 float4* __restrict__ xmean4) {
    int b  = blockIdx.x / 3;
    int c  = blockIdx.x % 3;
    int t  = threadIdx.x;
    int col = (t & 63) + c * 64;   // float4 column 0..191
    int sl  = t >> 6;              // 0..3
    const float4* xr = x4  + (long)b * S_ * D4_ + col;
    float4*       ow = out4 + ((long)b * 260 + 64) * D4_ + col;
    float4 acc = {0.f, 0.f, 0.f, 0.f};
    #pragma unroll 4
    for (int s = sl; s < S_; s += 4) {
        float4 v = xr[(long)s * D4_];
        acc.x += v.x; acc.y += v.y; acc.z += v.z; acc.w += v.w;
        ow[(long)s * D4_] = v;
    }
    __shared__ float4 part[256];
    part[t] = acc;
    __syncthreads();
    if (t < 64) {
        float4 a = part[t], b1 = part[t + 64], c1 = part[t + 128], d1 = part[t + 192];
        float4 m;
        m.x = (a.x + b1.x + c1.x + d1.x) / 196.f;
        m.y = (a.y + b1.y + c1.y + d1.y) / 196.f;
        m.z = (a.z + b1.z + c1.z + d1.z) / 196.f;
        m.w = (a.w + b1.w + c1.w + d1.w) / 196.f;
        xmean4[(long)b * D4_ + col] = m;
    }
}

// ---------------------------------------------------------------------------
// K2: prompt_key L2-normalize -> transposed [768,1024] only.
// block=192 (1 float4/thread), grid=1024 rows.
// ---------------------------------------------------------------------------
__global__ void l2normT_kernel(const float4* __restrict__ in4,
                               float* __restrict__ outT) {
    int r = blockIdx.x, t = threadIdx.x;   // t in [0,192)
    float4 v = in4[(long)r * D4_ + t];
    float ss = v.x * v.x + v.y * v.y + v.z * v.z + v.w * v.w;
    #pragma unroll
    for (int off = 32; off > 0; off >>= 1) ss += __shfl_xor(ss, off);
    __shared__ float wss[3];
    if ((t & 63) == 0) wss[t >> 6] = ss;
    __syncthreads();
    float tot = wss[0] + wss[1] + wss[2];
    float scale = 1.0f / sqrtf(fmaxf(tot, 1e-12f));
    int d = t * 4;
    outT[(long)d       * POOL_ + r] = v.x * scale;
    outT[(long)(d + 1) * POOL_ + r] = v.y * scale;
    outT[(long)(d + 2) * POOL_ + r] = v.z * scale;
    outT[(long)(d + 3) * POOL_ + r] = v.w * scale;
}

// ---------------------------------------------------------------------------
// K3: similarity = l2norm(xmean) [256,768] @ pnormT [768,1024] -> [256,1024]
// grid = (64 b-groups, 4 p-chunks), block = 256. Normalizes the 4 staged
// x rows in LDS (fuses the x l2norm).
// ---------------------------------------------------------------------------
__global__ void sim_kernel(const float* __restrict__ xmean,
                           const float* __restrict__ pT,
                           float* __restrict__ sim) {
    __shared__ float xs[4 * DIM_];
    __shared__ float scale[4];
    int bg = blockIdx.x;    // 0..63
    int pc = blockIdx.y;    // 0..3
    int t  = threadIdx.x;
    const float* xr = xmean + (long)bg * 4 * DIM_;
    for (int i = t; i < 4 * DIM_; i += 256) xs[i] = xr[i];
    __syncthreads();
    // wave w (0..3) computes the L2 scale of row w
    int w = t >> 6, lane = t & 63;
    float ss = 0.f;
    #pragma unroll
    for (int j = 0; j < 12; ++j) {
        float x = xs[w * DIM_ + lane + j * 64];
        ss += x * x;
    }
    #pragma unroll
    for (int off = 32; off > 0; off >>= 1) ss += __shfl_xor(ss, off);
    if (lane == 0) scale[w] = 1.0f / sqrtf(fmaxf(ss, 1e-12f));
    __syncthreads();
    for (int i = t; i < 4 * DIM_; i += 256) xs[i] *= scale[i / DIM_];
    __syncthreads();
    int p = pc * 256 + t;
    float a0 = 0.f, a1 = 0.f, a2 = 0.f, a3 = 0.f;
    const float* pcol = pT + p;
    #pragma unroll 4
    for (int d = 0; d < DIM_; ++d) {
        float wv = pcol[(long)d * POOL_];
        a0 += xs[d] * wv;
        a1 += xs[DIM_ + d] * wv;
        a2 += xs[2 * DIM_ + d] * wv;
        a3 += xs[3 * DIM_ + d] * wv;
    }
    long ob = (long)bg * 4 * POOL_ + p;
    sim[ob]             = a0;
    sim[ob + POOL_]     = a1;
    sim[ob + 2 * POOL_] = a2;
    sim[ob + 3 * POOL_] = a3;
}

// ---------------------------------------------------------------------------
// K4: per-row top-8 (ties -> smallest index) -> row_ids[row*8+k].
// One wave per row; writes all slots every call (no zeroing needed).
// ---------------------------------------------------------------------------
__global__ void row_topk_kernel(const float* __restrict__ sim,
                                int* __restrict__ row_ids) {
    int row  = blockIdx.x;
    int lane = threadIdx.x;      // 64
    float v[16];
    const float* r = sim + (long)row * POOL_;
    #pragma unroll
    for (int j = 0; j < 16; ++j) v[j] = r[lane + j * 64];
    for (int it = 0; it < TOPK_; ++it) {
        float bv = v[0];
        int   bi = lane;
        #pragma unroll
        for (int j = 1; j < 16; ++j) {
            if (v[j] > bv) { bv = v[j]; bi = lane + j * 64; }  // keep-first => smallest idx
        }
        #pragma unroll
        for (int off = 32; off > 0; off >>= 1) {
            float ov = __shfl_xor(bv, off);
            int   oi = __shfl_xor(bi, off);
            if (ov > bv || (ov == bv && oi < bi)) { bv = ov; bi = oi; }
        }
        if ((bi & 63) == lane) v[bi >> 6] = -INFINITY;
        if (lane == 0) row_ids[row * TOPK_ + it] = bi;
    }
}

// ---------------------------------------------------------------------------
// K5: consensus — LDS histogram of 2048 row ids -> top-8 of counts (ties ->
// smallest pool id) -> idx output + reduce_sim. Single block of 256.
// ---------------------------------------------------------------------------
__global__ void consensus_kernel(const int* __restrict__ row_ids,
                                 const float* __restrict__ sim,
                                 int* __restrict__ major,
                                 float* __restrict__ idx_out,
                                 float* __restrict__ rs_out) {
    __shared__ int   hist[POOL_];
    __shared__ int   maj[TOPK_];
    __shared__ float red[256];
    int t = threadIdx.x;  // 256
    #pragma unroll
    for (int j = 0; j < 4; ++j) hist[t + j * 256] = 0;
    __syncthreads();
    #pragma unroll
    for (int j = 0; j < TOPK_; ++j) atomicAdd(&hist[row_ids[t * TOPK_ + j]], 1);
    __syncthreads();
    if (t < 64) {
        int lane = t;
        int v[16];
        #pragma unroll
        for (int j = 0; j < 16; ++j) v[j] = hist[lane + j * 64];
        for (int it = 0; it < TOPK_; ++it) {
            int bv = v[0];
            int bi = lane;
            #pragma unroll
            for (int j = 1; j < 16; ++j) {
                if (v[j] > bv) { bv = v[j]; bi = lane + j * 64; }
            }
            #pragma unroll
            for (int off = 32; off > 0; off >>= 1) {
                int ov = __shfl_xor(bv, off);
                int oi = __shfl_xor(bi, off);
                if (ov > bv || (ov == bv && oi < bi)) { bv = ov; bi = oi; }
            }
            if (lane == 0) { maj[it] = bi; major[it] = bi; }
            if ((bi & 63) == lane) v[bi >> 6] = -1;
        }
    }
    __syncthreads();
    // idx output: [256,8] broadcast of maj
    for (int i = t; i < B_ * TOPK_; i += 256) idx_out[i] = (float)maj[i & 7];
    // reduce_sim: thread t == batch row t
    float s = 0.f;
    const float* r = sim + (long)t * POOL_;
    #pragma unroll
    for (int k = 0; k < TOPK_; ++k) s += r[maj[k]];
    red[t] = s;
    __syncthreads();
    for (int off = 128; off > 0; off >>= 1) {
        if (t < off) red[t] += red[t + off];
        __syncthreads();
    }
    if (t == 0) *rs_out = red[0] / (float)B_;
}

// ---------------------------------------------------------------------------
// K6: gather the 8 major prompts -> prompted_embedding[:, 0:64, :]
// ---------------------------------------------------------------------------
__global__ void gather_kernel(const float4* __restrict__ prompt4,
                              const int* __restrict__ major,
                              float4* __restrict__ out4) {
    long g = (long)blockIdx.x * 256 + threadIdx.x;  // < 256*64*192
    int d4 = (int)(g % D4_);
    int kl = (int)((g / D4_) % 64);
    int b  = (int)(g / (D4_ * 64));
    int k = kl >> 3, l = kl & 7;
    int pid = major[k];
    out4[((long)b * 260 + kl) * D4_ + d4] = prompt4[((long)pid * LEN_ + l) * D4_ + d4];
}

// ---------------------------------------------------------------------------
extern "C" void kernel_launch(void* const* d_in, const int* in_sizes, int n_in,
                              void* d_out, int out_size, void* d_ws, size_t ws_size,
                              hipStream_t stream) {
    const float* x_embed    = (const float*)d_in[0];
    const float* prompt     = (const float*)d_in[1];
    const float* prompt_key = (const float*)d_in[2];
    float* out = (float*)d_out;
    float* ws  = (float*)d_ws;

    float* xmean   = ws + WS_XMEAN;
    float* pnormT  = ws + WS_PNORMT;
    int*   row_ids = (int*)(ws + WS_ROWIDS);
    int*   major   = (int*)(ws + WS_MAJOR);

    float* out_pe  = out;                 // prompted_embedding
    float* out_rs  = out + RS_OFF;        // reduce_sim scalar
    float* out_sim = out + SIM_OFF;       // similarity [256,1024]
    float* out_idx = out + IDX_OFF;       // idx [256,8] (as float)

    // prompt_key -> pnormT (normalized, transposed)
    l2normT_kernel<<<POOL_, 192, 0, stream>>>((const float4*)prompt_key, pnormT);
    // mean over S + concat copy
    mean_copy_kernel<<<B_ * 3, 256, 0, stream>>>((const float4*)x_embed,
                                                 (float4*)out_pe, (float4*)xmean);
    // similarity (x l2norm fused)
    dim3 sgrid(64, 4);
    sim_kernel<<<sgrid, 256, 0, stream>>>(xmean, pnormT, out_sim);
    // per-row top-8 -> row_ids
    row_topk_kernel<<<B_, 64, 0, stream>>>(out_sim, row_ids);
    // consensus top-8 + idx + reduce_sim
    consensus_kernel<<<1, 256, 0, stream>>>(row_ids, out_sim, major, out_idx, out_rs);
    // gather prompts into output head
    gather_kernel<<<(B_ * 64 * D4_) / 256, 256, 0, stream>>>((const float4*)prompt,
                                                             major, (float4*)out_pe);
}

// Round 3
// 150.452 us; speedup vs baseline: 1.2383x; 1.1861x over previous
//
#include <hip/hip_runtime.h>
#include <math.h>

// Problem constants
#define B_    256
#define S_    196
#define DIM_  768
#define D4_   192          // DIM/4
#define POOL_ 1024
#define LEN_  8
#define TOPK_ 8

// Output layout (fp32, concatenated flat in return order)
//  prompted_embedding: [256, 260, 768]  = 51,118,080
//  reduce_sim        : scalar           = 1
//  similarity        : [256, 1024]      = 262,144
//  idx               : [256, 8]         = 2,048
#define RS_OFF     51118080L
#define SIM_OFF    51118081L
#define IDX_OFF    51380225L

// Workspace layout (float offsets)
#define WS_XMEAN   0L          // 256*768             = 196608
#define WS_PNORMT  196608L     // 768*1024 transposed = 786432
#define WS_ROWIDS  983040L     // 256*8 int
#define WS_MAJOR   985088L     // 8 int

// ---------------------------------------------------------------------------
// K1: fused prep. Blocks 0..255: per-batch-row contiguous copy + mean.
//     Blocks 256..511: prompt_key l2norm -> transposed pnormT (4 rows/block).
// block = 768 threads.
// ---------------------------------------------------------------------------
__global__ void __launch_bounds__(768) prep_kernel(
        const float4* __restrict__ x4,
        const float4* __restrict__ pk4,
        float4* __restrict__ out4,
        float4* __restrict__ xmean4,
        float* __restrict__ pT) {
    int t = threadIdx.x;   // 0..767
    if (blockIdx.x < B_) {
        // ---- mean + contiguous copy for batch row b ----
        int b = blockIdx.x;
        const float4* xr = x4 + (long)b * (S_ * D4_);          // 196*192 float4, contiguous
        float4* ow = out4 + ((long)b * 260 + 64) * D4_;        // contiguous dest
        float4 acc = {0.f, 0.f, 0.f, 0.f};
        // 196*192 = 37632 = 49 * 768;  (t + k*768) % 192 == t % 192  (768%192==0)
        #pragma unroll 7
        for (int k = 0; k < 49; ++k) {
            int i = t + k * 768;
            float4 v = xr[i];
            acc.x += v.x; acc.y += v.y; acc.z += v.z; acc.w += v.w;
            ow[i] = v;
        }
        __shared__ float4 part[768];
        part[t] = acc;
        __syncthreads();
        if (t < 192) {
            float4 a = part[t], b1 = part[t + 192], c1 = part[t + 384], d1 = part[t + 576];
            float4 m;
            m.x = (a.x + b1.x + c1.x + d1.x) / 196.f;
            m.y = (a.y + b1.y + c1.y + d1.y) / 196.f;
            m.z = (a.z + b1.z + c1.z + d1.z) / 196.f;
            m.w = (a.w + b1.w + c1.w + d1.w) / 196.f;
            xmean4[(long)b * D4_ + t] = m;
        }
    } else {
        // ---- prompt_key l2norm, 4 rows per block (group = 3 waves) ----
        int r0 = (blockIdx.x - B_) * 4;
        int g = t / 192, i = t % 192;   // group 0..3 == waves [3g,3g+2]
        int r = r0 + g;
        float4 v = pk4[(long)r * D4_ + i];
        float ss = v.x * v.x + v.y * v.y + v.z * v.z + v.w * v.w;
        #pragma unroll
        for (int off = 32; off > 0; off >>= 1) ss += __shfl_xor(ss, off);
        __shared__ float wss[12];
        if ((t & 63) == 0) wss[t >> 6] = ss;
        __syncthreads();
        float tot = wss[3 * g] + wss[3 * g + 1] + wss[3 * g + 2];
        float sc = 1.0f / sqrtf(fmaxf(tot, 1e-12f));
        int d = i * 4;
        pT[(long)d       * POOL_ + r] = v.x * sc;
        pT[(long)(d + 1) * POOL_ + r] = v.y * sc;
        pT[(long)(d + 2) * POOL_ + r] = v.z * sc;
        pT[(long)(d + 3) * POOL_ + r] = v.w * sc;
    }
}

// ---------------------------------------------------------------------------
// K2: similarity + per-row top-8, fused. grid = 64 blocks x 1024 threads.
// Block bg owns batch rows 4bg..4bg+3 and ALL 1024 pool columns.
// x l2norm fused on the LDS-staged rows. Per-row top-8 done by waves 0..3.
// ---------------------------------------------------------------------------
__global__ void __launch_bounds__(1024) sim_topk_kernel(
        const float* __restrict__ xmean,
        const float* __restrict__ pT,
        float* __restrict__ sim,
        int* __restrict__ row_ids) {
    __shared__ float xs[4 * DIM_];
    __shared__ float scale[4];
    __shared__ float simbuf[4][POOL_];
    int bg = blockIdx.x;    // 0..63
    int t  = threadIdx.x;   // 0..1023
    const float* xr = xmean + (long)bg * 4 * DIM_;
    for (int i = t; i < 4 * DIM_; i += 1024) xs[i] = xr[i];
    __syncthreads();
    int w = t >> 6, lane = t & 63;
    if (w < 4) {
        float ss = 0.f;
        #pragma unroll
        for (int j = 0; j < 12; ++j) {
            float x = xs[w * DIM_ + lane + j * 64];
            ss += x * x;
        }
        #pragma unroll
        for (int off = 32; off > 0; off >>= 1) ss += __shfl_xor(ss, off);
        if (lane == 0) scale[w] = 1.0f / sqrtf(fmaxf(ss, 1e-12f));
    }
    __syncthreads();
    for (int i = t; i < 4 * DIM_; i += 1024) xs[i] *= scale[i / DIM_];
    __syncthreads();
    // dot products: thread t -> pool column p = t
    float a0 = 0.f, a1 = 0.f, a2 = 0.f, a3 = 0.f;
    const float* pcol = pT + t;
    #pragma unroll 8
    for (int d = 0; d < DIM_; ++d) {
        float wv = pcol[(long)d * POOL_];
        a0 += xs[d] * wv;
        a1 += xs[DIM_ + d] * wv;
        a2 += xs[2 * DIM_ + d] * wv;
        a3 += xs[3 * DIM_ + d] * wv;
    }
    long ob = (long)bg * 4 * POOL_ + t;
    sim[ob]             = a0;
    sim[ob + POOL_]     = a1;
    sim[ob + 2 * POOL_] = a2;
    sim[ob + 3 * POOL_] = a3;
    simbuf[0][t] = a0; simbuf[1][t] = a1; simbuf[2][t] = a2; simbuf[3][t] = a3;
    __syncthreads();
    // per-row top-8 (ties -> smallest pool index); wave w handles row w
    if (w < 4) {
        float v[16];
        #pragma unroll
        for (int j = 0; j < 16; ++j) v[j] = simbuf[w][lane + j * 64];
        for (int it = 0; it < TOPK_; ++it) {
            float bv = v[0];
            int   bi = lane;
            #pragma unroll
            for (int j = 1; j < 16; ++j) {
                if (v[j] > bv) { bv = v[j]; bi = lane + j * 64; }  // keep-first => smallest idx
            }
            #pragma unroll
            for (int off = 32; off > 0; off >>= 1) {
                float ov = __shfl_xor(bv, off);
                int   oi = __shfl_xor(bi, off);
                if (ov > bv || (ov == bv && oi < bi)) { bv = ov; bi = oi; }
            }
            if ((bi & 63) == lane) v[bi >> 6] = -INFINITY;
            if (lane == 0) row_ids[(bg * 4 + w) * TOPK_ + it] = bi;
        }
    }
}

// ---------------------------------------------------------------------------
// K3: consensus — LDS histogram of 2048 row ids -> top-8 of counts (ties ->
// smallest pool id) -> idx output + reduce_sim. Single block of 256.
// ---------------------------------------------------------------------------
__global__ void consensus_kernel(const int* __restrict__ row_ids,
                                 const float* __restrict__ sim,
                                 int* __restrict__ major,
                                 float* __restrict__ idx_out,
                                 float* __restrict__ rs_out) {
    __shared__ int   hist[POOL_];
    __shared__ int   maj[TOPK_];
    __shared__ float red[256];
    int t = threadIdx.x;  // 256
    #pragma unroll
    for (int j = 0; j < 4; ++j) hist[t + j * 256] = 0;
    __syncthreads();
    #pragma unroll
    for (int j = 0; j < TOPK_; ++j) atomicAdd(&hist[row_ids[t * TOPK_ + j]], 1);
    __syncthreads();
    if (t < 64) {
        int lane = t;
        int v[16];
        #pragma unroll
        for (int j = 0; j < 16; ++j) v[j] = hist[lane + j * 64];
        for (int it = 0; it < TOPK_; ++it) {
            int bv = v[0];
            int bi = lane;
            #pragma unroll
            for (int j = 1; j < 16; ++j) {
                if (v[j] > bv) { bv = v[j]; bi = lane + j * 64; }
            }
            #pragma unroll
            for (int off = 32; off > 0; off >>= 1) {
                int ov = __shfl_xor(bv, off);
                int oi = __shfl_xor(bi, off);
                if (ov > bv || (ov == bv && oi < bi)) { bv = ov; bi = oi; }
            }
            if (lane == 0) { maj[it] = bi; major[it] = bi; }
            if ((bi & 63) == lane) v[bi >> 6] = -1;
        }
    }
    __syncthreads();
    // idx output: [256,8] broadcast of maj
    for (int i = t; i < B_ * TOPK_; i += 256) idx_out[i] = (float)maj[i & 7];
    // reduce_sim: thread t == batch row t
    float s = 0.f;
    const float* r = sim + (long)t * POOL_;
    #pragma unroll
    for (int k = 0; k < TOPK_; ++k) s += r[maj[k]];
    red[t] = s;
    __syncthreads();
    for (int off = 128; off > 0; off >>= 1) {
        if (t < off) red[t] += red[t + off];
        __syncthreads();
    }
    if (t == 0) *rs_out = red[0] / (float)B_;
}

// ---------------------------------------------------------------------------
// K4: gather the 8 major prompts -> prompted_embedding[:, 0:64, :]
// grid-stride over 256*64*192 float4s.
// ---------------------------------------------------------------------------
__global__ void gather_kernel(const float4* __restrict__ prompt4,
                              const int* __restrict__ major,
                              float4* __restrict__ out4) {
    __shared__ int maj[TOPK_];
    if (threadIdx.x < TOPK_) maj[threadIdx.x] = major[threadIdx.x];
    __syncthreads();
    const long total = (long)B_ * 64 * D4_;
    for (long g = (long)blockIdx.x * blockDim.x + threadIdx.x; g < total;
         g += (long)gridDim.x * blockDim.x) {
        int  d4 = (int)(g % D4_);
        long q  = g / D4_;
        int  kl = (int)(q & 63);
        int  b  = (int)(q >> 6);
        int  pid = maj[kl >> 3];
        int  l   = kl & 7;
        out4[((long)b * 260 + kl) * D4_ + d4] = prompt4[((long)pid * LEN_ + l) * D4_ + d4];
    }
}

// ---------------------------------------------------------------------------
extern "C" void kernel_launch(void* const* d_in, const int* in_sizes, int n_in,
                              void* d_out, int out_size, void* d_ws, size_t ws_size,
                              hipStream_t stream) {
    const float* x_embed    = (const float*)d_in[0];
    const float* prompt     = (const float*)d_in[1];
    const float* prompt_key = (const float*)d_in[2];
    float* out = (float*)d_out;
    float* ws  = (float*)d_ws;

    float* xmean   = ws + WS_XMEAN;
    float* pnormT  = ws + WS_PNORMT;
    int*   row_ids = (int*)(ws + WS_ROWIDS);
    int*   major   = (int*)(ws + WS_MAJOR);

    float* out_pe  = out;                 // prompted_embedding
    float* out_rs  = out + RS_OFF;        // reduce_sim scalar
    float* out_sim = out + SIM_OFF;       // similarity [256,1024]
    float* out_idx = out + IDX_OFF;       // idx [256,8] (as float)

    // fused: mean+copy (blocks 0..255) and prompt_key l2normT (blocks 256..511)
    prep_kernel<<<512, 768, 0, stream>>>((const float4*)x_embed,
                                         (const float4*)prompt_key,
                                         (float4*)out_pe, (float4*)xmean, pnormT);
    // similarity + per-row top-8
    sim_topk_kernel<<<64, 1024, 0, stream>>>(xmean, pnormT, out_sim, row_ids);
    // consensus top-8 + idx + reduce_sim
    consensus_kernel<<<1, 256, 0, stream>>>(row_ids, out_sim, major, out_idx, out_rs);
    // gather prompts into output head
    gather_kernel<<<2048, 256, 0, stream>>>((const float4*)prompt, major, (float4*)out_pe);
}

// Round 4
// 121.577 us; speedup vs baseline: 1.5324x; 1.2375x over previous
//
#include <hip/hip_runtime.h>
#include <math.h>

// Problem constants
#define B_    256
#define S_    196
#define DIM_  768
#define D4_   192          // DIM/4
#define POOL_ 1024
#define LEN_  8
#define TOPK_ 8

// Output layout (fp32, concatenated flat in return order)
//  prompted_embedding: [256, 260, 768]  = 51,118,080
//  reduce_sim        : scalar           = 1
//  similarity        : [256, 1024]      = 262,144
//  idx               : [256, 8]         = 2,048
#define RS_OFF     51118080L
#define SIM_OFF    51118081L
#define IDX_OFF    51380225L

// Workspace layout (float offsets)
#define WS_XNORM   0L          // 256*768             = 196608
#define WS_PNORMT  196608L     // 768*1024 transposed = 786432
#define WS_PART    983040L     // 4*256*1024 partials = 1048576
#define WS_ROWIDS  2031616L    // 256*8 int
#define WS_MAJOR   2032128L    // 8 int
// total: 2,032,136 floats = 8.13 MB (< round-1's proven 7.9 MB + margin)

// ---------------------------------------------------------------------------
// K1: fused prep. Blocks 0..255: per-batch-row contiguous copy + mean + l2norm.
//     Blocks 256..511: prompt_key l2norm -> transposed pnormT (4 rows/block).
// block = 768 threads.
// ---------------------------------------------------------------------------
__global__ void __launch_bounds__(768) prep_kernel(
        const float4* __restrict__ x4,
        const float4* __restrict__ pk4,
        float4* __restrict__ out4,
        float4* __restrict__ xnorm4,
        float* __restrict__ pT) {
    __shared__ float4 part[768];
    __shared__ float  sred[192];
    __shared__ float  sscale;
    __shared__ float  wss[12];
    int t = threadIdx.x;   // 0..767
    if (blockIdx.x < B_) {
        // ---- mean + contiguous copy + l2norm for batch row b ----
        int b = blockIdx.x;
        const float4* xr = x4 + (long)b * (S_ * D4_);          // contiguous 588 KB
        float4* ow = out4 + ((long)b * 260 + 64) * D4_;        // contiguous dest
        float4 acc = {0.f, 0.f, 0.f, 0.f};
        // 196*192 = 37632 = 49 * 768; (t + k*768) % 192 == t % 192
        #pragma unroll 7
        for (int k = 0; k < 49; ++k) {
            int i = t + k * 768;
            float4 v = xr[i];
            acc.x += v.x; acc.y += v.y; acc.z += v.z; acc.w += v.w;
            ow[i] = v;
        }
        part[t] = acc;
        __syncthreads();
        float4 m = {0.f, 0.f, 0.f, 0.f};
        if (t < 192) {
            float4 a = part[t], b1 = part[t + 192], c1 = part[t + 384], d1 = part[t + 576];
            m.x = (a.x + b1.x + c1.x + d1.x) / 196.f;
            m.y = (a.y + b1.y + c1.y + d1.y) / 196.f;
            m.z = (a.z + b1.z + c1.z + d1.z) / 196.f;
            m.w = (a.w + b1.w + c1.w + d1.w) / 196.f;
            sred[t] = m.x * m.x + m.y * m.y + m.z * m.z + m.w * m.w;
        }
        __syncthreads();
        if (t < 64) {
            float s2 = sred[t] + sred[t + 64] + sred[t + 128];
            #pragma unroll
            for (int off = 32; off > 0; off >>= 1) s2 += __shfl_xor(s2, off);
            if (t == 0) sscale = 1.0f / sqrtf(fmaxf(s2, 1e-12f));
        }
        __syncthreads();
        if (t < 192) {
            float sc = sscale;
            float4 o = {m.x * sc, m.y * sc, m.z * sc, m.w * sc};
            xnorm4[(long)b * D4_ + t] = o;
        }
    } else {
        // ---- prompt_key l2norm, 4 rows per block (group = 3 waves) ----
        int r0 = (blockIdx.x - B_) * 4;
        int g = t / 192, i = t % 192;   // group 0..3 == waves [3g,3g+2]
        int r = r0 + g;
        float4 v = pk4[(long)r * D4_ + i];
        float ss = v.x * v.x + v.y * v.y + v.z * v.z + v.w * v.w;
        #pragma unroll
        for (int off = 32; off > 0; off >>= 1) ss += __shfl_xor(ss, off);
        if ((t & 63) == 0) wss[t >> 6] = ss;
        __syncthreads();
        float tot = wss[3 * g] + wss[3 * g + 1] + wss[3 * g + 2];
        float sc = 1.0f / sqrtf(fmaxf(tot, 1e-12f));
        int d = i * 4;
        pT[(long)d       * POOL_ + r] = v.x * sc;
        pT[(long)(d + 1) * POOL_ + r] = v.y * sc;
        pT[(long)(d + 2) * POOL_ + r] = v.z * sc;
        pT[(long)(d + 3) * POOL_ + r] = v.w * sc;
    }
}

// ---------------------------------------------------------------------------
// K2: similarity partials. grid = (64 bg, 4 dc), block = 512.
// Block computes rows 4bg..4bg+3 x all 1024 cols over d-chunk dc (192 d's),
// split 2-way across threads (ds). Thread owns 4 rows x 4 consecutive cols.
// ---------------------------------------------------------------------------
__global__ void __launch_bounds__(512) simpart_kernel(
        const float4* __restrict__ xnorm4,
        const float4* __restrict__ pT4,    // [768][256] float4
        float4* __restrict__ part4) {      // [4dc][256row][256colquad]
    __shared__ float4 xs4[4 * 48];         // [row][48] f4 = 192 d's chunk
    __shared__ float4 red4[4 * 256];       // [row][colquad]
    int bg = blockIdx.x;     // 0..63
    int dc = blockIdx.y;     // 0..3
    int t  = threadIdx.x;    // 0..511
    int p4 = t & 255;        // colquad: cols 4*p4..4*p4+3
    int ds = t >> 8;         // 0/1 half of the d-chunk
    if (t < 192) {
        int r = t / 48, q = t % 48;
        xs4[r * 48 + q] = xnorm4[(long)(bg * 4 + r) * D4_ + dc * 48 + q];
    }
    __syncthreads();
    float4 a0 = {0,0,0,0}, a1 = {0,0,0,0}, a2 = {0,0,0,0}, a3 = {0,0,0,0};
    int qbase = ds * 24;
    const float4* pbase = pT4 + ((long)dc * 192 + ds * 96) * 256 + p4;
    #pragma unroll 2
    for (int q = 0; q < 24; ++q) {
        float4 xa = xs4[qbase + q];
        float4 xb = xs4[48 + qbase + q];
        float4 xc = xs4[96 + qbase + q];
        float4 xd = xs4[144 + qbase + q];
        const float* xaf = (const float*)&xa;
        const float* xbf = (const float*)&xb;
        const float* xcf = (const float*)&xc;
        const float* xdf = (const float*)&xd;
        #pragma unroll
        for (int j = 0; j < 4; ++j) {
            float4 w = pbase[(q * 4 + j) * 256];
            a0.x += xaf[j] * w.x; a0.y += xaf[j] * w.y; a0.z += xaf[j] * w.z; a0.w += xaf[j] * w.w;
            a1.x += xbf[j] * w.x; a1.y += xbf[j] * w.y; a1.z += xbf[j] * w.z; a1.w += xbf[j] * w.w;
            a2.x += xcf[j] * w.x; a2.y += xcf[j] * w.y; a2.z += xcf[j] * w.z; a2.w += xcf[j] * w.w;
            a3.x += xdf[j] * w.x; a3.y += xdf[j] * w.y; a3.z += xdf[j] * w.z; a3.w += xdf[j] * w.w;
        }
    }
    if (ds == 1) {
        red4[p4]       = a0;
        red4[256 + p4] = a1;
        red4[512 + p4] = a2;
        red4[768 + p4] = a3;
    }
    __syncthreads();
    if (ds == 0) {
        float4 b0 = red4[p4], b1 = red4[256 + p4], b2 = red4[512 + p4], b3 = red4[768 + p4];
        a0.x += b0.x; a0.y += b0.y; a0.z += b0.z; a0.w += b0.w;
        a1.x += b1.x; a1.y += b1.y; a1.z += b1.z; a1.w += b1.w;
        a2.x += b2.x; a2.y += b2.y; a2.z += b2.z; a2.w += b2.w;
        a3.x += b3.x; a3.y += b3.y; a3.z += b3.z; a3.w += b3.w;
        long base = ((long)dc * 256 + bg * 4) * 256 + p4;
        part4[base]       = a0;
        part4[base + 256] = a1;
        part4[base + 512] = a2;
        part4[base + 768] = a3;
    }
}

// ---------------------------------------------------------------------------
// K3: sum 4 partials per row -> sim; per-row top-8 (ties -> smallest index).
// grid = 256 (one wave per row).
// ---------------------------------------------------------------------------
__global__ void topk_sum_kernel(const float* __restrict__ part,
                                float* __restrict__ sim,
                                int* __restrict__ row_ids) {
    int row  = blockIdx.x;
    int lane = threadIdx.x;      // 64
    float v[16];
    #pragma unroll
    for (int j = 0; j < 16; ++j) {
        int p = lane + j * 64;
        float s = part[(long)row * POOL_ + p]
                + part[(long)(256 + row) * POOL_ + p]
                + part[(long)(512 + row) * POOL_ + p]
                + part[(long)(768 + row) * POOL_ + p];
        v[j] = s;
        sim[(long)row * POOL_ + p] = s;
    }
    for (int it = 0; it < TOPK_; ++it) {
        float bv = v[0];
        int   bi = lane;
        #pragma unroll
        for (int j = 1; j < 16; ++j) {
            if (v[j] > bv) { bv = v[j]; bi = lane + j * 64; }  // keep-first => smallest idx
        }
        #pragma unroll
        for (int off = 32; off > 0; off >>= 1) {
            float ov = __shfl_xor(bv, off);
            int   oi = __shfl_xor(bi, off);
            if (ov > bv || (ov == bv && oi < bi)) { bv = ov; bi = oi; }
        }
        if ((bi & 63) == lane) v[bi >> 6] = -INFINITY;
        if (lane == 0) row_ids[row * TOPK_ + it] = bi;
    }
}

// ---------------------------------------------------------------------------
// K4: consensus — LDS histogram of 2048 row ids -> top-8 of counts (ties ->
// smallest pool id) -> idx output + reduce_sim. Single block of 256.
// ---------------------------------------------------------------------------
__global__ void consensus_kernel(const int* __restrict__ row_ids,
                                 const float* __restrict__ sim,
                                 int* __restrict__ major,
                                 float* __restrict__ idx_out,
                                 float* __restrict__ rs_out) {
    __shared__ int   hist[POOL_];
    __shared__ int   maj[TOPK_];
    __shared__ float red[256];
    int t = threadIdx.x;  // 256
    #pragma unroll
    for (int j = 0; j < 4; ++j) hist[t + j * 256] = 0;
    __syncthreads();
    #pragma unroll
    for (int j = 0; j < TOPK_; ++j) atomicAdd(&hist[row_ids[t * TOPK_ + j]], 1);
    __syncthreads();
    if (t < 64) {
        int lane = t;
        int v[16];
        #pragma unroll
        for (int j = 0; j < 16; ++j) v[j] = hist[lane + j * 64];
        for (int it = 0; it < TOPK_; ++it) {
            int bv = v[0];
            int bi = lane;
            #pragma unroll
            for (int j = 1; j < 16; ++j) {
                if (v[j] > bv) { bv = v[j]; bi = lane + j * 64; }
            }
            #pragma unroll
            for (int off = 32; off > 0; off >>= 1) {
                int ov = __shfl_xor(bv, off);
                int oi = __shfl_xor(bi, off);
                if (ov > bv || (ov == bv && oi < bi)) { bv = ov; bi = oi; }
            }
            if (lane == 0) { maj[it] = bi; major[it] = bi; }
            if ((bi & 63) == lane) v[bi >> 6] = -1;
        }
    }
    __syncthreads();
    // idx output: [256,8] broadcast of maj
    for (int i = t; i < B_ * TOPK_; i += 256) idx_out[i] = (float)maj[i & 7];
    // reduce_sim: thread t == batch row t
    float s = 0.f;
    const float* r = sim + (long)t * POOL_;
    #pragma unroll
    for (int k = 0; k < TOPK_; ++k) s += r[maj[k]];
    red[t] = s;
    __syncthreads();
    for (int off = 128; off > 0; off >>= 1) {
        if (t < off) red[t] += red[t + off];
        __syncthreads();
    }
    if (t == 0) *rs_out = red[0] / (float)B_;
}

// ---------------------------------------------------------------------------
// K5: gather the 8 major prompts -> prompted_embedding[:, 0:64, :]
// grid-stride over 256*64*192 float4s.
// ---------------------------------------------------------------------------
__global__ void gather_kernel(const float4* __restrict__ prompt4,
                              const int* __restrict__ major,
                              float4* __restrict__ out4) {
    __shared__ int maj[TOPK_];
    if (threadIdx.x < TOPK_) maj[threadIdx.x] = major[threadIdx.x];
    __syncthreads();
    const long total = (long)B_ * 64 * D4_;
    for (long g = (long)blockIdx.x * blockDim.x + threadIdx.x; g < total;
         g += (long)gridDim.x * blockDim.x) {
        int  d4 = (int)(g % D4_);
        long q  = g / D4_;
        int  kl = (int)(q & 63);
        int  b  = (int)(q >> 6);
        int  pid = maj[kl >> 3];
        int  l   = kl & 7;
        out4[((long)b * 260 + kl) * D4_ + d4] = prompt4[((long)pid * LEN_ + l) * D4_ + d4];
    }
}

// ---------------------------------------------------------------------------
extern "C" void kernel_launch(void* const* d_in, const int* in_sizes, int n_in,
                              void* d_out, int out_size, void* d_ws, size_t ws_size,
                              hipStream_t stream) {
    const float* x_embed    = (const float*)d_in[0];
    const float* prompt     = (const float*)d_in[1];
    const float* prompt_key = (const float*)d_in[2];
    float* out = (float*)d_out;
    float* ws  = (float*)d_ws;

    float* xnorm   = ws + WS_XNORM;
    float* pnormT  = ws + WS_PNORMT;
    float* partial = ws + WS_PART;
    int*   row_ids = (int*)(ws + WS_ROWIDS);
    int*   major   = (int*)(ws + WS_MAJOR);

    float* out_pe  = out;                 // prompted_embedding
    float* out_rs  = out + RS_OFF;        // reduce_sim scalar
    float* out_sim = out + SIM_OFF;       // similarity [256,1024]
    float* out_idx = out + IDX_OFF;       // idx [256,8] (as float)

    // fused: mean+copy+l2norm (blocks 0..255) and prompt_key l2normT (256..511)
    prep_kernel<<<512, 768, 0, stream>>>((const float4*)x_embed,
                                         (const float4*)prompt_key,
                                         (float4*)out_pe, (float4*)xnorm, pnormT);
    // similarity partials over the whole chip
    dim3 sgrid(64, 4);
    simpart_kernel<<<sgrid, 512, 0, stream>>>((const float4*)xnorm,
                                              (const float4*)pnormT,
                                              (float4*)partial);
    // sum partials + per-row top-8
    topk_sum_kernel<<<B_, 64, 0, stream>>>(partial, out_sim, row_ids);
    // consensus top-8 + idx + reduce_sim
    consensus_kernel<<<1, 256, 0, stream>>>(row_ids, out_sim, major, out_idx, out_rs);
    // gather prompts into output head
    gather_kernel<<<2048, 256, 0, stream>>>((const float4*)prompt, major, (float4*)out_pe);
}